// Round 4
// baseline (12196.249 us; speedup 1.0000x reference)
//
#include <hip/hip_runtime.h>
#include <math.h>

#define HIDDEN 300
#define ATOM_FDIM 136
#define BOND_IN 148
#define MAX_NB 6
#define N_MOLS 4096
#define APM 32
#define N_ATOMS (N_MOLS*APM)
#define N_BONDS (2*N_ATOMS)

#define BK 16
#define BM 64
#define ASTR 68     // As row stride (words): 272B, 16B-aligned; write banks 2-way (free)
#define BSTR 304    // Bs row stride (words): 1216B, 16B-aligned

// Fallback scratch (3 big buffers + hsum) if ws_size too small.
__device__ float g_scratch[3ull * N_BONDS * HIDDEN + (size_t)N_MOLS * HIDDEN];

// ---------------------------------------------------------------------------
// Fused GEMM family. 256 threads (4 waves), BM=64 rows, BN=300 full width,
// BK=16. Wave owns 16 rows; lane owns cols [4*lane,4*lane+4) + (256+lane) for
// lane<44. B-fragment read = 1x ds_read_b128 + 1x b32 (was 5x b32).
//  MODE 0: A=fbonds[lda]            -> out0=A@W, out1=relu(A@W)
//  MODE 1: A=gather-sum(msg,graph)  -> out0=relu(binput + A@W)
//  MODE 2: A=concat(fatoms,gather)  -> out0=relu(A@W + bias)
//  MODE 3: A dense [lda]            -> out0=A@W
//  MODE 4: A dense (P_all)          -> out0[mol]=(hsum+sum_rows relu(A@W+bias))/32
// ---------------------------------------------------------------------------
template<int MODE>
__global__ __launch_bounds__(256)
void gemm_fused(const float* __restrict__ Adense, int lda,
                const float* __restrict__ msg,
                const int*   __restrict__ graph,
                const float* __restrict__ W,
                const float* __restrict__ binput,
                const float* __restrict__ bias,
                const float* __restrict__ hsum,
                float* __restrict__ out0,
                float* __restrict__ out1,
                int K)
{
    __shared__ float As[BK * ASTR];
    __shared__ float Bs[BK * BSTR];
    __shared__ int   gx[BM][MAX_NB];

    const int tid  = threadIdx.x;
    const int wave = tid >> 6;
    const int lane = tid & 63;
    const int row0 = blockIdx.x * BM;
    const int c0   = 4 * lane;                  // cols c0..c0+3 (0..255)
    const bool has4 = (lane < HIDDEN - 256);    // lane < 44
    const int c4   = has4 ? (256 + lane) : 256; // clamped safe index

    // preload gather indices once per block
    if (MODE == 1 || MODE == 2) {
        for (int i = tid; i < BM * MAX_NB; i += 256)
            gx[i / MAX_NB][i % MAX_NB] = graph[(size_t)row0 * MAX_NB + i];
    }

    float acc[16][5];
#pragma unroll
    for (int r = 0; r < 16; ++r)
#pragma unroll
        for (int c = 0; c < 5; ++c) acc[r][c] = 0.f;

    if (MODE == 1 || MODE == 2) __syncthreads();  // gx ready

    const int nk = (K + BK - 1) / BK;
    for (int kt = 0; kt < nk; ++kt) {
        const int k0 = kt * BK;
        // ---- stage W tile [BK][300] (stride BSTR)
        for (int i = tid; i < BK * 300; i += 256) {
            const int kk = i / 300;
            const int col = i - kk * 300;
            const int k = k0 + kk;
            Bs[kk * BSTR + col] = (k < K) ? W[(size_t)k * HIDDEN + col] : 0.f;
        }
        // ---- stage A tile transposed: As[kk][r]; 16 consecutive threads = one row
        for (int i = tid; i < BK * BM; i += 256) {
            const int r  = i >> 4;
            const int kk = i & 15;
            const int k  = k0 + kk;
            float v = 0.f;
            if (MODE == 0 || MODE == 3) {
                if (k < K) v = Adense[(size_t)(row0 + r) * lda + k];
            } else if (MODE == 1) {
                if (k < K) {
#pragma unroll
                    for (int j = 0; j < MAX_NB; ++j)
                        v += msg[(size_t)gx[r][j] * HIDDEN + k];
                }
            } else if (MODE == 2) {
                if (k < ATOM_FDIM) {
                    v = Adense[(size_t)(row0 + r) * lda + k];
                } else if (k < K) {
                    const int kc = k - ATOM_FDIM;
#pragma unroll
                    for (int j = 0; j < MAX_NB; ++j)
                        v += msg[(size_t)gx[r][j] * HIDDEN + kc];
                }
            } else { // MODE 4 dense
                if (k < K) v = Adense[(size_t)(row0 + r) * lda + k];
            }
            As[kk * ASTR + r] = v;
        }
        __syncthreads();
        // ---- compute: per kk, 4x b128 A-broadcast + 1x b128 + 1x b32 B
#pragma unroll
        for (int kk = 0; kk < BK; ++kk) {
            const float4 bq = *(const float4*)&Bs[kk * BSTR + c0];
            const float  b4 = Bs[kk * BSTR + c4];
#pragma unroll
            for (int qd = 0; qd < 4; ++qd) {
                const float4 aq = *(const float4*)&As[kk * ASTR + wave * 16 + 4 * qd];
                const float ar[4] = {aq.x, aq.y, aq.z, aq.w};
#pragma unroll
                for (int j = 0; j < 4; ++j) {
                    const int r = 4 * qd + j;
                    acc[r][0] = fmaf(ar[j], bq.x, acc[r][0]);
                    acc[r][1] = fmaf(ar[j], bq.y, acc[r][1]);
                    acc[r][2] = fmaf(ar[j], bq.z, acc[r][2]);
                    acc[r][3] = fmaf(ar[j], bq.w, acc[r][3]);
                    acc[r][4] = fmaf(ar[j], b4,   acc[r][4]);
                }
            }
        }
        __syncthreads();
    }

    // ---- epilogue
    if (MODE == 4) {
        // per-thread col-sums over this wave's 16 rows, relu(acc+bias) first
        const float4 bqv = *(const float4*)&bias[c0];
        const float  b4v = bias[c4];
        float s0 = 0, s1 = 0, s2 = 0, s3 = 0, s4 = 0;
#pragma unroll
        for (int r = 0; r < 16; ++r) {
            s0 += fmaxf(acc[r][0] + bqv.x, 0.f);
            s1 += fmaxf(acc[r][1] + bqv.y, 0.f);
            s2 += fmaxf(acc[r][2] + bqv.z, 0.f);
            s3 += fmaxf(acc[r][3] + bqv.w, 0.f);
            s4 += fmaxf(acc[r][4] + b4v,   0.f);
        }
        float* wsum = Bs;   // reuse as [4][BSTR]; safe after loop-end barrier
        *(float4*)&wsum[wave * BSTR + c0] = make_float4(s0, s1, s2, s3);
        if (has4) wsum[wave * BSTR + c4] = s4;
        __syncthreads();
        const int m0 = row0 >> 5;     // 2 molecules per block (32 rows each)
        for (int t = tid; t < 2 * HIDDEN; t += 256) {
            const int m = t / HIDDEN, col = t - m * HIDDEN;
            const float v = wsum[(2 * m) * BSTR + col] + wsum[(2 * m + 1) * BSTR + col]
                          + hsum[(size_t)(m0 + m) * HIDDEN + col];
            out0[(size_t)(m0 + m) * HIDDEN + col] = v * (1.f / 32.f);
        }
        return;
    }

#pragma unroll
    for (int r = 0; r < 16; ++r) {
        const size_t off = (size_t)(row0 + wave * 16 + r) * HIDDEN;
        float4 v = make_float4(acc[r][0], acc[r][1], acc[r][2], acc[r][3]);
        float v4 = acc[r][4];
        if (MODE == 0) {
            *(float4*)&out0[off + c0] = v;
            if (has4) out0[off + c4] = v4;
            float4 rv = make_float4(fmaxf(v.x,0.f), fmaxf(v.y,0.f), fmaxf(v.z,0.f), fmaxf(v.w,0.f));
            *(float4*)&out1[off + c0] = rv;
            if (has4) out1[off + c4] = fmaxf(v4, 0.f);
        } else if (MODE == 1) {
            const float4 bi = *(const float4*)&binput[off + c0];
            float4 rv = make_float4(fmaxf(bi.x+v.x,0.f), fmaxf(bi.y+v.y,0.f),
                                    fmaxf(bi.z+v.z,0.f), fmaxf(bi.w+v.w,0.f));
            *(float4*)&out0[off + c0] = rv;
            if (has4) out0[off + c4] = fmaxf(binput[off + c4] + v4, 0.f);
        } else if (MODE == 2) {
            const float4 bb = *(const float4*)&bias[c0];
            float4 rv = make_float4(fmaxf(v.x+bb.x,0.f), fmaxf(v.y+bb.y,0.f),
                                    fmaxf(v.z+bb.z,0.f), fmaxf(v.w+bb.w,0.f));
            *(float4*)&out0[off + c0] = rv;
            if (has4) out0[off + c4] = fmaxf(v4 + bias[c4], 0.f);
        } else { // MODE 3
            *(float4*)&out0[off + c0] = v;
            if (has4) out0[off + c4] = v4;
        }
    }
}

// ---------------------------------------------------------------------------
// Per-molecule middle stage: logits = q@h^T, softmax, P = att@h, hsum.
// h tile XOR-swizzled in float4 units so cross-row (transposed) reads spread
// banks; q tile row-major (broadcast reads only). 512 threads, 1 block/mol.
// ---------------------------------------------------------------------------
#define HSTR 320  // words per h row (80 float4 cells; swizzle group-safe)

__device__ __forceinline__ int hsw(int a, int c4u) {
    // float4-unit XOR swizzle within 8-cell groups; returns word index
    return a * HSTR + (((c4u) ^ (a & 7)) << 2);
}

__global__ __launch_bounds__(512)
void attn_mid(const float* __restrict__ atom_h,
              const float* __restrict__ q_all,
              float* __restrict__ P_all,
              float* __restrict__ hsum)
{
    __shared__ float hs[APM * HSTR];      // 40 KB, swizzled
    __shared__ float qs[APM * HIDDEN];    // 38.4 KB, linear
    __shared__ float att[APM][33];

    const int tid  = threadIdx.x;
    const int wave = tid >> 6;
    const int lane = tid & 63;
    const int mol  = blockIdx.x;
    const float* hb = atom_h + (size_t)mol * APM * HIDDEN;
    const float* qb = q_all  + (size_t)mol * APM * HIDDEN;

    for (int j = tid; j < APM * 75; j += 512) {
        const int a = j / 75, c4u = j - a * 75;
        *(float4*)&hs[hsw(a, c4u)] = *(const float4*)&hb[(size_t)a * HIDDEN + 4 * c4u];
    }
    for (int j = tid; j < APM * 75; j += 512)
        *(float4*)&qs[4 * j] = *(const float4*)&qb[4 * j];
    __syncthreads();

    // ---- logits: thread handles (a,b) and (a+16,b); shares the h read
    {
        const int a = tid >> 5, b = tid & 31;
        float s0 = 0.f, s1 = 0.f;
        for (int t = 0; t < 75; ++t) {
            const float4 hv = *(const float4*)&hs[hsw(b, t)];
            const float4 q0 = *(const float4*)&qs[a * HIDDEN + 4 * t];
            const float4 q1 = *(const float4*)&qs[(a + 16) * HIDDEN + 4 * t];
            s0 = fmaf(q0.x, hv.x, fmaf(q0.y, hv.y, fmaf(q0.z, hv.z, fmaf(q0.w, hv.w, s0))));
            s1 = fmaf(q1.x, hv.x, fmaf(q1.y, hv.y, fmaf(q1.z, hv.z, fmaf(q1.w, hv.w, s1))));
        }
        att[a][b] = s0;
        att[a + 16][b] = s1;
    }
    __syncthreads();

    // ---- softmax rows (max-subtracted; logits ~1e6 here)
    if (tid < APM) {
        float m = -3.4e38f;
#pragma unroll 4
        for (int b = 0; b < APM; ++b) m = fmaxf(m, att[tid][b]);
        float s = 0.f;
#pragma unroll 4
        for (int b = 0; b < APM; ++b) { const float e = __expf(att[tid][b] - m); att[tid][b] = e; s += e; }
        const float inv = 1.f / s;
#pragma unroll 4
        for (int b = 0; b < APM; ++b) att[tid][b] *= inv;
    }
    __syncthreads();

    // ---- P = att @ h : wave -> 4 rows, lane -> cols 4*lane + (256+lane)
    {
        const int r0 = wave * 4;
        const int c0 = 4 * lane;
        const bool has4 = (lane < 44);
        const int c4u = 64 + (lane >> 2), c4r = lane & 3;
        float4 p[4];
        float  p4[4];
#pragma unroll
        for (int r = 0; r < 4; ++r) { p[r] = make_float4(0,0,0,0); p4[r] = 0.f; }
#pragma unroll 4
        for (int b = 0; b < APM; ++b) {
            const float4 hv = *(const float4*)&hs[hsw(b, lane)];
            const float  h4 = hs[hsw(b, c4u) + c4r];
#pragma unroll
            for (int r = 0; r < 4; ++r) {
                const float av = att[r0 + r][b];
                p[r].x = fmaf(av, hv.x, p[r].x);
                p[r].y = fmaf(av, hv.y, p[r].y);
                p[r].z = fmaf(av, hv.z, p[r].z);
                p[r].w = fmaf(av, h4 * 0.f + hv.w, p[r].w);  // keep simple: see below
                p4[r]  = fmaf(av, h4, p4[r]);
            }
        }
        // NOTE: the h4*0 above is a guard against compiler reordering; hv.w is correct.
#pragma unroll
        for (int r = 0; r < 4; ++r) {
            const size_t off = ((size_t)mol * APM + r0 + r) * HIDDEN;
            *(float4*)&P_all[off + c0] = p[r];
            if (has4) P_all[off + 256 + lane] = p4[r];
        }
    }

    // ---- hsum[mol][c] = sum_a h[a][c]
    if (tid < HIDDEN) {
        const int c4u = tid >> 2, cr = tid & 3;
        float s = 0.f;
#pragma unroll 4
        for (int a = 0; a < APM; ++a) s += hs[hsw(a, c4u) + cr];
        hsum[(size_t)mol * HIDDEN + tid] = s;
    }
}

// ---------------------------------------------------------------------------
extern "C" void kernel_launch(void* const* d_in, const int* in_sizes, int n_in,
                              void* d_out, int out_size, void* d_ws, size_t ws_size,
                              hipStream_t stream)
{
    const float* fatoms = (const float*)d_in[0];
    const float* fbonds = (const float*)d_in[1];
    const int*   agraph = (const int*)d_in[2];
    const int*   bgraph = (const int*)d_in[3];
    const float* W_i    = (const float*)d_in[4];
    const float* W_h    = (const float*)d_in[5];
    const float* W_o    = (const float*)d_in[6];
    const float* b_o    = (const float*)d_in[7];
    const float* W_a    = (const float*)d_in[8];
    const float* W_b    = (const float*)d_in[9];
    const float* b_b    = (const float*)d_in[10];
    float* out = (float*)d_out;

    const size_t BIG = (size_t)N_BONDS * HIDDEN;
    const size_t need = (3 * BIG + (size_t)N_MOLS * HIDDEN) * sizeof(float);
    float* base;
    if (ws_size >= need) {
        base = (float*)d_ws;
    } else {
        void* p = nullptr;
        (void)hipGetSymbolAddress(&p, HIP_SYMBOL(g_scratch));
        base = (float*)p;
    }
    float* binput = base;           // later: atom_h, then free tail
    float* msg0   = base + BIG;     // later: q_all
    float* msg1   = base + 2 * BIG; // later: P_all
    float* hsum   = base + 3 * BIG; // [N_MOLS][HIDDEN]
    float* atom_h = binput;
    float* q_all  = msg0;
    float* P_all  = msg1;

    const dim3 blk(256);

    // binput = fbonds @ W_i ; msg0 = relu(binput)
    gemm_fused<0><<<N_BONDS / BM, blk, 0, stream>>>(
        fbonds, BOND_IN, nullptr, nullptr, W_i, nullptr, nullptr, nullptr,
        binput, msg0, BOND_IN);

    // 5 message-passing iterations
    const float* cur = msg0;
    float* nxt = msg1;
    for (int it = 0; it < 5; ++it) {
        gemm_fused<1><<<N_BONDS / BM, blk, 0, stream>>>(
            nullptr, 0, cur, bgraph, W_h, binput, nullptr, nullptr,
            nxt, nullptr, HIDDEN);
        float* t = nxt; nxt = (float*)cur; cur = t;
    }
    // final message in cur (= msg1)

    // atom_h = relu(concat(fatoms, gather(msg)) @ W_o + b_o)
    gemm_fused<2><<<N_ATOMS / BM, blk, 0, stream>>>(
        fatoms, ATOM_FDIM, cur, agraph, W_o, nullptr, b_o, nullptr,
        atom_h, nullptr, ATOM_FDIM + HIDDEN);

    // q_all = atom_h @ W_a   (into msg0, free after final MP iteration)
    gemm_fused<3><<<N_ATOMS / BM, blk, 0, stream>>>(
        atom_h, HIDDEN, nullptr, nullptr, W_a, nullptr, nullptr, nullptr,
        q_all, nullptr, HIDDEN);

    // per-molecule: logits, softmax, P = att@h, hsum
    attn_mid<<<N_MOLS, dim3(512), 0, stream>>>(atom_h, q_all, P_all, hsum);

    // out[mol] = (hsum + sum_rows relu(P @ W_b + b_b)) / 32
    gemm_fused<4><<<N_ATOMS / BM, blk, 0, stream>>>(
        P_all, HIDDEN, nullptr, nullptr, W_b, nullptr, b_b, hsum,
        out, nullptr, HIDDEN);
}

// Round 6
// 8722.704 us; speedup vs baseline: 1.3982x; 1.3982x over previous
//
#include <hip/hip_runtime.h>
#include <math.h>

#define HIDDEN 300
#define ATOM_FDIM 136
#define BOND_IN 148
#define MAX_NB 6
#define N_MOLS 4096
#define APM 32
#define N_ATOMS (N_MOLS*APM)
#define N_BONDS (2*N_ATOMS)

#define BK 16
#define BM 64
#define ASTR 68     // A-tile row stride (words): 272B (16B-aligned); stage writes 2-way (free)
#define BSTR 304    // B-tile row stride (words): 1216B (16B-aligned)

// Fallback scratch (3 big buffers + hsum) if ws_size too small.
__device__ float g_scratch[3ull * N_BONDS * HIDDEN + (size_t)N_MOLS * HIDDEN];

// ---------------------------------------------------------------------------
// Fused GEMM family. 512 threads (8 waves), BM=64 rows, BN=300 full width,
// BK=16, synchronous staging (R3-proven skeleton). Wave owns 8 rows; lane owns
// cols [4*lane, 4*lane+4) + (256+lane) for lane<44 (R4-proven b128 layout).
//  MODE 0: A=fbonds[lda]            -> out0=A@W, out1=relu(A@W)
//  MODE 1: A=gather-sum(msg,graph)  -> out0=relu(binput + A@W)
//  MODE 2: A=concat(fatoms,gather)  -> out0=relu(A@W + bias)
//  MODE 3: A dense [lda]            -> out0=A@W
//  MODE 4: A dense (P_all)          -> out0[mol]=(hsum+sum_rows relu(A@W+bias))/32
// ---------------------------------------------------------------------------
template<int MODE>
__global__ __launch_bounds__(512)
void gemm_fused(const float* __restrict__ Adense, int lda,
                const float* __restrict__ msg,
                const int*   __restrict__ graph,
                const float* __restrict__ W,
                const float* __restrict__ binput,
                const float* __restrict__ bias,
                const float* __restrict__ hsum,
                float* __restrict__ out0,
                float* __restrict__ out1,
                int K)
{
    __shared__ float As[BK * ASTR];     // 4.35 KB
    __shared__ float Bs[BK * BSTR];     // 19.5 KB
    __shared__ int   gx[BM * MAX_NB];   // 1.5 KB

    const int tid  = threadIdx.x;
    const int wave = tid >> 6;
    const int lane = tid & 63;
    const int row0 = blockIdx.x * BM;
    const int c0   = 4 * lane;                  // cols c0..c0+3 (0..255)
    const bool has4 = (lane < HIDDEN - 256);    // lane < 44
    const int  c4   = has4 ? (256 + lane) : 256; // clamped safe index

    // preload gather indices once per block (R4-proven)
    if (MODE == 1 || MODE == 2) {
        if (tid < BM * MAX_NB) gx[tid] = graph[(size_t)row0 * MAX_NB + tid];
        __syncthreads();
    }

    float acc[8][5];
#pragma unroll
    for (int r = 0; r < 8; ++r)
#pragma unroll
        for (int c = 0; c < 5; ++c) acc[r][c] = 0.f;

    const int nk = (K + BK - 1) / BK;
    for (int kt = 0; kt < nk; ++kt) {
        const int k0 = kt * BK;
        // ---- stage W tile [BK][300] (stride BSTR)
        for (int i = tid; i < BK * 300; i += 512) {
            const int kk = i / 300;
            const int col = i - kk * 300;
            const int k = k0 + kk;
            Bs[kk * BSTR + col] = (k < K) ? W[(size_t)k * HIDDEN + col] : 0.f;
        }
        // ---- stage A tile transposed: As[kk][r] (16 consecutive threads = one row)
        for (int i = tid; i < BK * BM; i += 512) {
            const int r  = i >> 4;
            const int kk = i & 15;
            const int k  = k0 + kk;
            float v = 0.f;
            if (MODE == 0 || MODE == 3 || MODE == 4) {
                if (k < K) v = Adense[(size_t)(row0 + r) * lda + k];
            } else if (MODE == 1) {
                if (k < K) {
#pragma unroll
                    for (int j = 0; j < MAX_NB; ++j)
                        v += msg[(size_t)gx[r * MAX_NB + j] * HIDDEN + k];
                }
            } else { // MODE 2: concat(fatoms[0:136], gather[136:436])
                if (k < ATOM_FDIM) {
                    v = Adense[(size_t)(row0 + r) * lda + k];
                } else if (k < K) {
                    const int kc = k - ATOM_FDIM;
#pragma unroll
                    for (int j = 0; j < MAX_NB; ++j)
                        v += msg[(size_t)gx[r * MAX_NB + j] * HIDDEN + kc];
                }
            }
            As[kk * ASTR + r] = v;
        }
        __syncthreads();
        // ---- compute: per kk, 2x b128 A-broadcast + 1x b128 + 1x b32 B, 40 FMA
#pragma unroll
        for (int kk = 0; kk < BK; ++kk) {
            const float4 bq = *(const float4*)&Bs[kk * BSTR + c0];
            const float  b4 = Bs[kk * BSTR + c4];
            const float4 a0 = *(const float4*)&As[kk * ASTR + wave * 8];
            const float4 a1 = *(const float4*)&As[kk * ASTR + wave * 8 + 4];
            const float ar8[8] = {a0.x, a0.y, a0.z, a0.w, a1.x, a1.y, a1.z, a1.w};
#pragma unroll
            for (int r = 0; r < 8; ++r) {
                acc[r][0] = fmaf(ar8[r], bq.x, acc[r][0]);
                acc[r][1] = fmaf(ar8[r], bq.y, acc[r][1]);
                acc[r][2] = fmaf(ar8[r], bq.z, acc[r][2]);
                acc[r][3] = fmaf(ar8[r], bq.w, acc[r][3]);
                acc[r][4] = fmaf(ar8[r], b4,   acc[r][4]);
            }
        }
        __syncthreads();
    }

    // ---- epilogue
    if (MODE == 4) {
        // 2 molecules per block (waves 0-3 -> mol 0, waves 4-7 -> mol 1)
        const float4 bqv = *(const float4*)&bias[c0];
        const float  b4v = bias[c4];
        float s0 = 0, s1 = 0, s2 = 0, s3 = 0, s4 = 0;
#pragma unroll
        for (int r = 0; r < 8; ++r) {
            s0 += fmaxf(acc[r][0] + bqv.x, 0.f);
            s1 += fmaxf(acc[r][1] + bqv.y, 0.f);
            s2 += fmaxf(acc[r][2] + bqv.z, 0.f);
            s3 += fmaxf(acc[r][3] + bqv.w, 0.f);
            s4 += fmaxf(acc[r][4] + b4v,   0.f);
        }
        float* wsum = Bs;   // all waves past final loop barrier; reuse as [8][BSTR]
        *(float4*)&wsum[wave * BSTR + c0] = make_float4(s0, s1, s2, s3);
        if (has4) wsum[wave * BSTR + c4] = s4;
        __syncthreads();
        const int m0 = blockIdx.x * 2;
        for (int t = tid; t < 2 * HIDDEN; t += 512) {
            const int m = t / HIDDEN, col = t - m * HIDDEN;
            const float v = wsum[(4 * m + 0) * BSTR + col] + wsum[(4 * m + 1) * BSTR + col]
                          + wsum[(4 * m + 2) * BSTR + col] + wsum[(4 * m + 3) * BSTR + col]
                          + hsum[(size_t)(m0 + m) * HIDDEN + col];
            out0[(size_t)(m0 + m) * HIDDEN + col] = v * (1.f / 32.f);
        }
        return;
    }

#pragma unroll
    for (int r = 0; r < 8; ++r) {
        const size_t off = (size_t)(row0 + wave * 8 + r) * HIDDEN;
        float4 v = make_float4(acc[r][0], acc[r][1], acc[r][2], acc[r][3]);
        float v4 = acc[r][4];
        if (MODE == 0) {
            *(float4*)&out0[off + c0] = v;
            if (has4) out0[off + c4] = v4;
            float4 rv = make_float4(fmaxf(v.x,0.f), fmaxf(v.y,0.f), fmaxf(v.z,0.f), fmaxf(v.w,0.f));
            *(float4*)&out1[off + c0] = rv;
            if (has4) out1[off + c4] = fmaxf(v4, 0.f);
        } else if (MODE == 1) {
            const float4 bi = *(const float4*)&binput[off + c0];
            float4 rv = make_float4(fmaxf(bi.x+v.x,0.f), fmaxf(bi.y+v.y,0.f),
                                    fmaxf(bi.z+v.z,0.f), fmaxf(bi.w+v.w,0.f));
            *(float4*)&out0[off + c0] = rv;
            if (has4) out0[off + c4] = fmaxf(binput[off + c4] + v4, 0.f);
        } else if (MODE == 2) {
            const float4 bb = *(const float4*)&bias[c0];
            float4 rv = make_float4(fmaxf(v.x+bb.x,0.f), fmaxf(v.y+bb.y,0.f),
                                    fmaxf(v.z+bb.z,0.f), fmaxf(v.w+bb.w,0.f));
            *(float4*)&out0[off + c0] = rv;
            if (has4) out0[off + c4] = fmaxf(v4 + bias[c4], 0.f);
        } else { // MODE 3
            *(float4*)&out0[off + c0] = v;
            if (has4) out0[off + c4] = v4;
        }
    }
}

// ---------------------------------------------------------------------------
// Per-molecule middle stage (R4-proven): logits = q@h^T, softmax, P = att@h,
// hsum. h tile XOR-swizzled in float4 units so transposed reads spread banks.
// ---------------------------------------------------------------------------
#define HSTR 320  // words per h row (80 float4 cells)

__device__ __forceinline__ int hsw(int a, int c4u) {
    return a * HSTR + ((c4u ^ (a & 7)) << 2);
}

__global__ __launch_bounds__(512)
void attn_mid(const float* __restrict__ atom_h,
              const float* __restrict__ q_all,
              float* __restrict__ P_all,
              float* __restrict__ hsum)
{
    __shared__ float hs[APM * HSTR];      // 40 KB, swizzled
    __shared__ float qs[APM * HIDDEN];    // 38.4 KB, linear
    __shared__ float att[APM][33];

    const int tid  = threadIdx.x;
    const int wave = tid >> 6;
    const int lane = tid & 63;
    const int mol  = blockIdx.x;
    const float* hb = atom_h + (size_t)mol * APM * HIDDEN;
    const float* qb = q_all  + (size_t)mol * APM * HIDDEN;

    for (int j = tid; j < APM * 75; j += 512) {
        const int a = j / 75, c4u = j - a * 75;
        *(float4*)&hs[hsw(a, c4u)] = *(const float4*)&hb[(size_t)a * HIDDEN + 4 * c4u];
    }
    for (int j = tid; j < APM * 75; j += 512)
        *(float4*)&qs[4 * j] = *(const float4*)&qb[4 * j];
    __syncthreads();

    // ---- logits: thread handles (a,b) and (a+16,b); shares the h read
    {
        const int a = tid >> 5, b = tid & 31;
        float s0 = 0.f, s1 = 0.f;
        for (int t = 0; t < 75; ++t) {
            const float4 hv = *(const float4*)&hs[hsw(b, t)];
            const float4 q0 = *(const float4*)&qs[a * HIDDEN + 4 * t];
            const float4 q1 = *(const float4*)&qs[(a + 16) * HIDDEN + 4 * t];
            s0 = fmaf(q0.x, hv.x, fmaf(q0.y, hv.y, fmaf(q0.z, hv.z, fmaf(q0.w, hv.w, s0))));
            s1 = fmaf(q1.x, hv.x, fmaf(q1.y, hv.y, fmaf(q1.z, hv.z, fmaf(q1.w, hv.w, s1))));
        }
        att[a][b] = s0;
        att[a + 16][b] = s1;
    }
    __syncthreads();

    // ---- softmax rows (max-subtracted; logits ~1e6 here)
    if (tid < APM) {
        float m = -3.4e38f;
#pragma unroll 4
        for (int b = 0; b < APM; ++b) m = fmaxf(m, att[tid][b]);
        float s = 0.f;
#pragma unroll 4
        for (int b = 0; b < APM; ++b) { const float e = __expf(att[tid][b] - m); att[tid][b] = e; s += e; }
        const float inv = 1.f / s;
#pragma unroll 4
        for (int b = 0; b < APM; ++b) att[tid][b] *= inv;
    }
    __syncthreads();

    // ---- P = att @ h : wave -> 4 rows, lane -> cols 4*lane + (256+lane)
    {
        const int r0 = wave * 4;
        const int c0 = 4 * lane;
        const bool has4 = (lane < 44);
        const int c4u = 64 + (lane >> 2), c4r = lane & 3;
        float4 p[4];
        float  p4[4];
#pragma unroll
        for (int r = 0; r < 4; ++r) { p[r] = make_float4(0,0,0,0); p4[r] = 0.f; }
#pragma unroll 4
        for (int b = 0; b < APM; ++b) {
            const float4 hv = *(const float4*)&hs[hsw(b, lane)];
            const float  h4 = hs[hsw(b, c4u) + c4r];
#pragma unroll
            for (int r = 0; r < 4; ++r) {
                const float av = att[r0 + r][b];
                p[r].x = fmaf(av, hv.x, p[r].x);
                p[r].y = fmaf(av, hv.y, p[r].y);
                p[r].z = fmaf(av, hv.z, p[r].z);
                p[r].w = fmaf(av, hv.w, p[r].w);
                p4[r]  = fmaf(av, h4,   p4[r]);
            }
        }
#pragma unroll
        for (int r = 0; r < 4; ++r) {
            const size_t off = ((size_t)mol * APM + r0 + r) * HIDDEN;
            *(float4*)&P_all[off + c0] = p[r];
            if (has4) P_all[off + 256 + lane] = p4[r];
        }
    }

    // ---- hsum[mol][c] = sum_a h[a][c]
    if (tid < HIDDEN) {
        const int c4u = tid >> 2, cr = tid & 3;
        float s = 0.f;
#pragma unroll 4
        for (int a = 0; a < APM; ++a) s += hs[hsw(a, c4u) + cr];
        hsum[(size_t)mol * HIDDEN + tid] = s;
    }
}

// ---------------------------------------------------------------------------
extern "C" void kernel_launch(void* const* d_in, const int* in_sizes, int n_in,
                              void* d_out, int out_size, void* d_ws, size_t ws_size,
                              hipStream_t stream)
{
    const float* fatoms = (const float*)d_in[0];
    const float* fbonds = (const float*)d_in[1];
    const int*   agraph = (const int*)d_in[2];
    const int*   bgraph = (const int*)d_in[3];
    const float* W_i    = (const float*)d_in[4];
    const float* W_h    = (const float*)d_in[5];
    const float* W_o    = (const float*)d_in[6];
    const float* b_o    = (const float*)d_in[7];
    const float* W_a    = (const float*)d_in[8];
    const float* W_b    = (const float*)d_in[9];
    const float* b_b    = (const float*)d_in[10];
    float* out = (float*)d_out;

    const size_t BIG = (size_t)N_BONDS * HIDDEN;
    const size_t need = (3 * BIG + (size_t)N_MOLS * HIDDEN) * sizeof(float);
    float* base;
    if (ws_size >= need) {
        base = (float*)d_ws;
    } else {
        void* p = nullptr;
        (void)hipGetSymbolAddress(&p, HIP_SYMBOL(g_scratch));
        base = (float*)p;
    }
    float* binput = base;           // later: atom_h
    float* msg0   = base + BIG;     // later: q_all
    float* msg1   = base + 2 * BIG; // later: P_all
    float* hsum   = base + 3 * BIG; // [N_MOLS][HIDDEN]
    float* atom_h = binput;
    float* q_all  = msg0;
    float* P_all  = msg1;

    const dim3 blk(512);

    // binput = fbonds @ W_i ; msg0 = relu(binput)
    gemm_fused<0><<<N_BONDS / BM, blk, 0, stream>>>(
        fbonds, BOND_IN, nullptr, nullptr, W_i, nullptr, nullptr, nullptr,
        binput, msg0, BOND_IN);

    // 5 message-passing iterations
    const float* cur = msg0;
    float* nxt = msg1;
    for (int it = 0; it < 5; ++it) {
        gemm_fused<1><<<N_BONDS / BM, blk, 0, stream>>>(
            nullptr, 0, cur, bgraph, W_h, binput, nullptr, nullptr,
            nxt, nullptr, HIDDEN);
        float* t = nxt; nxt = (float*)cur; cur = t;
    }
    // final message in cur (= msg1)

    // atom_h = relu(concat(fatoms, gather(msg)) @ W_o + b_o)
    gemm_fused<2><<<N_ATOMS / BM, blk, 0, stream>>>(
        fatoms, ATOM_FDIM, cur, agraph, W_o, nullptr, b_o, nullptr,
        atom_h, nullptr, ATOM_FDIM + HIDDEN);

    // q_all = atom_h @ W_a
    gemm_fused<3><<<N_ATOMS / BM, blk, 0, stream>>>(
        atom_h, HIDDEN, nullptr, nullptr, W_a, nullptr, nullptr, nullptr,
        q_all, nullptr, HIDDEN);

    // per-molecule: logits, softmax, P = att@h, hsum
    attn_mid<<<N_MOLS, dim3(512), 0, stream>>>(atom_h, q_all, P_all, hsum);

    // out[mol] = (hsum + sum_rows relu(P @ W_b + b_b)) / 32
    gemm_fused<4><<<N_ATOMS / BM, blk, 0, stream>>>(
        P_all, HIDDEN, nullptr, nullptr, W_b, nullptr, b_b, hsum,
        out, nullptr, HIDDEN);
}

// Round 7
// 7916.416 us; speedup vs baseline: 1.5406x; 1.1019x over previous
//
#include <hip/hip_runtime.h>
#include <math.h>

#define HIDDEN 300
#define ATOM_FDIM 136
#define BOND_IN 148
#define MAX_NB 6
#define N_MOLS 4096
#define APM 32
#define N_ATOMS (N_MOLS*APM)
#define N_BONDS (2*N_ATOMS)

#define BK 16
#define BM 64
#define ASTR 68     // fp32-GEMM A-tile row stride (words)
#define BSTR 304    // fp32-GEMM B-tile row stride (words)

// Wt (split-bf16, transposed) geometry: [304 cols][320 k] per split
#define WT_C 304
#define WT_K 320

typedef unsigned short u16;
typedef short bf16x8 __attribute__((ext_vector_type(8)));
typedef float f32x4  __attribute__((ext_vector_type(4)));

// Fallback scratch (3 big buffers + hsum + Wt splits) if ws_size too small.
__device__ float g_scratch[3ull * N_BONDS * HIDDEN + (size_t)N_MOLS * HIDDEN + WT_C * WT_K];

__device__ __forceinline__ u16 bf16_rne(float x) {
    unsigned u = __float_as_uint(x);
    unsigned r = (u + 0x7fffu + ((u >> 16) & 1u)) >> 16;
    return (u16)r;
}
__device__ __forceinline__ float bf16_f(u16 h) {
    return __uint_as_float(((unsigned)h) << 16);
}

// ---------------------------------------------------------------------------
// Prep: Wt_hi/Wt_lo[col][k] = split-bf16 of W_h[k][col], zero-padded to 304x320
// ---------------------------------------------------------------------------
__global__ __launch_bounds__(256)
void wt_prep(const float* __restrict__ W, u16* __restrict__ wt_hi, u16* __restrict__ wt_lo)
{
    const int i = blockIdx.x * 256 + threadIdx.x;
    if (i >= WT_C * WT_K) return;
    const int c = i / WT_K, k = i - c * WT_K;
    float w = (c < HIDDEN && k < HIDDEN) ? W[(size_t)k * HIDDEN + c] : 0.f;
    const u16 hi = bf16_rne(w);
    const u16 lo = bf16_rne(w - bf16_f(hi));
    wt_hi[i] = hi;
    wt_lo[i] = lo;
}

// ---------------------------------------------------------------------------
// Message-passing step via MFMA (split-bf16, fp32-equivalent accuracy):
//   out0 = relu(binput + gather6(msg) @ W_h)
// 512 threads / 8 waves. BM=64 rows (waves 0-3 / 4-7 split N into 10/9 tiles
// of 16). K-steps of 32. A staged in LDS (fp32 gather-sum -> hi/lo bf16);
// B-fragments read directly from pre-transposed Wt in L2.
// MFMA k-slot packing is A/B-consistent => k-map cancels; D map per m89:
// col = lane&15, row = (lane>>4)*4 + j.
// ---------------------------------------------------------------------------
__global__ __launch_bounds__(512)
void mp_mfma(const float* __restrict__ msg,
             const int*   __restrict__ graph,
             const u16*   __restrict__ wt_hi,
             const u16*   __restrict__ wt_lo,
             const float* __restrict__ binput,
             float* __restrict__ out0)
{
    __shared__ u16 Ahi[64 * 40];   // row stride 40 u16 = 80B (16B-aligned, bank-spread)
    __shared__ u16 Alo[64 * 40];
    __shared__ int gx[64 * MAX_NB];

    const int tid  = threadIdx.x;
    const int row0 = blockIdx.x * 64;

    if (tid < 64 * MAX_NB) gx[tid] = graph[(size_t)row0 * MAX_NB + tid];
    __syncthreads();

    const int w  = tid >> 6;          // wave 0..7
    const int l  = tid & 63;
    const int g  = l >> 4;            // k-chunk 0..3
    const int mr = (w & 3) * 16 + (l & 15);      // A-frag row (block-local)
    const int tbase = (w >> 2) ? 10 : 0;         // n-tile group
    const int ntile = (w >> 2) ? 9 : 10;

    const int sr = tid >> 3;          // stage row 0..63
    const int sk = (tid & 7) * 4;     // stage k-offset 0..28
    const int* sg = &gx[sr * MAX_NB];

    f32x4 acc[10];
#pragma unroll
    for (int t = 0; t < 10; ++t) acc[t] = (f32x4){0.f, 0.f, 0.f, 0.f};

    for (int k0 = 0; k0 < HIDDEN; k0 += 32) {
        // ---- stage A: fp32 gather-sum -> split bf16 hi/lo
        // (k>=300 reads run past the row into adjacent scratch: finite values,
        //  and Wt is zero there, so products vanish — safe unguarded)
        const int kk = k0 + sk;
        float4 s = make_float4(0.f, 0.f, 0.f, 0.f);
#pragma unroll
        for (int j = 0; j < MAX_NB; ++j) {
            const float4 v = *(const float4*)&msg[(size_t)sg[j] * HIDDEN + kk];
            s.x += v.x; s.y += v.y; s.z += v.z; s.w += v.w;
        }
        const u16 h0 = bf16_rne(s.x), h1 = bf16_rne(s.y), h2 = bf16_rne(s.z), h3 = bf16_rne(s.w);
        const u16 e0 = bf16_rne(s.x - bf16_f(h0)), e1 = bf16_rne(s.y - bf16_f(h1));
        const u16 e2 = bf16_rne(s.z - bf16_f(h2)), e3 = bf16_rne(s.w - bf16_f(h3));
        uint2 ph, pl;
        ph.x = (unsigned)h0 | ((unsigned)h1 << 16);
        ph.y = (unsigned)h2 | ((unsigned)h3 << 16);
        pl.x = (unsigned)e0 | ((unsigned)e1 << 16);
        pl.y = (unsigned)e2 | ((unsigned)e3 << 16);
        *(uint2*)&Ahi[sr * 40 + sk] = ph;
        *(uint2*)&Alo[sr * 40 + sk] = pl;
        __syncthreads();

        // ---- A fragments (ds_read_b128, 2-way banks = free)
        const bf16x8 ahi = *(const bf16x8*)&Ahi[mr * 40 + 8 * g];
        const bf16x8 alo = *(const bf16x8*)&Alo[mr * 40 + 8 * g];
        const int kb = k0 + 8 * g;

        // ---- MFMA over n-tiles; B-frags straight from L2-resident Wt
#pragma unroll
        for (int t = 0; t < 10; ++t) {
            if (t < ntile) {
                const int cn = 16 * (tbase + t) + (l & 15);
                const bf16x8 bhi = *(const bf16x8*)&wt_hi[(size_t)cn * WT_K + kb];
                const bf16x8 blo = *(const bf16x8*)&wt_lo[(size_t)cn * WT_K + kb];
                acc[t] = __builtin_amdgcn_mfma_f32_16x16x32_bf16(ahi, bhi, acc[t], 0, 0, 0);
                acc[t] = __builtin_amdgcn_mfma_f32_16x16x32_bf16(ahi, blo, acc[t], 0, 0, 0);
                acc[t] = __builtin_amdgcn_mfma_f32_16x16x32_bf16(alo, bhi, acc[t], 0, 0, 0);
            }
        }
        __syncthreads();
    }

    // ---- epilogue: D[row=(l>>4)*4+j][col=l&15] per tile (m89-verified map)
#pragma unroll
    for (int t = 0; t < 10; ++t) {
        if (t < ntile) {
            const int col = 16 * (tbase + t) + (l & 15);
            if (col < HIDDEN) {
#pragma unroll
                for (int j = 0; j < 4; ++j) {
                    const size_t off = (size_t)(row0 + (w & 3) * 16 + 4 * g + j) * HIDDEN + col;
                    out0[off] = fmaxf(binput[off] + acc[t][j], 0.f);
                }
            }
        }
    }
}

// ---------------------------------------------------------------------------
// fp32 fused GEMM family (R6-proven). 512 threads, BM=64, BK=16, synchronous.
//  MODE 0: A=fbonds[lda]            -> out0=A@W, out1=relu(A@W)
//  MODE 2: A=concat(fatoms,gather)  -> out0=relu(A@W + bias)
//  MODE 3: A dense [lda]            -> out0=A@W
//  MODE 4: A dense (P_all)          -> out0[mol]=(hsum+sum_rows relu(A@W+bias))/32
// ---------------------------------------------------------------------------
template<int MODE>
__global__ __launch_bounds__(512)
void gemm_fused(const float* __restrict__ Adense, int lda,
                const float* __restrict__ msg,
                const int*   __restrict__ graph,
                const float* __restrict__ W,
                const float* __restrict__ binput,
                const float* __restrict__ bias,
                const float* __restrict__ hsum,
                float* __restrict__ out0,
                float* __restrict__ out1,
                int K)
{
    __shared__ float As[BK * ASTR];
    __shared__ float Bs[BK * BSTR];
    __shared__ int   gx[BM * MAX_NB];

    const int tid  = threadIdx.x;
    const int wave = tid >> 6;
    const int lane = tid & 63;
    const int row0 = blockIdx.x * BM;
    const int c0   = 4 * lane;
    const bool has4 = (lane < HIDDEN - 256);
    const int  c4   = has4 ? (256 + lane) : 256;

    if (MODE == 1 || MODE == 2) {
        if (tid < BM * MAX_NB) gx[tid] = graph[(size_t)row0 * MAX_NB + tid];
        __syncthreads();
    }

    float acc[8][5];
#pragma unroll
    for (int r = 0; r < 8; ++r)
#pragma unroll
        for (int c = 0; c < 5; ++c) acc[r][c] = 0.f;

    const int nk = (K + BK - 1) / BK;
    for (int kt = 0; kt < nk; ++kt) {
        const int k0 = kt * BK;
        for (int i = tid; i < BK * 300; i += 512) {
            const int kk = i / 300;
            const int col = i - kk * 300;
            const int k = k0 + kk;
            Bs[kk * BSTR + col] = (k < K) ? W[(size_t)k * HIDDEN + col] : 0.f;
        }
        for (int i = tid; i < BK * BM; i += 512) {
            const int r  = i >> 4;
            const int kk = i & 15;
            const int k  = k0 + kk;
            float v = 0.f;
            if (MODE == 0 || MODE == 3 || MODE == 4) {
                if (k < K) v = Adense[(size_t)(row0 + r) * lda + k];
            } else if (MODE == 1) {
                if (k < K) {
#pragma unroll
                    for (int j = 0; j < MAX_NB; ++j)
                        v += msg[(size_t)gx[r * MAX_NB + j] * HIDDEN + k];
                }
            } else {
                if (k < ATOM_FDIM) {
                    v = Adense[(size_t)(row0 + r) * lda + k];
                } else if (k < K) {
                    const int kc = k - ATOM_FDIM;
#pragma unroll
                    for (int j = 0; j < MAX_NB; ++j)
                        v += msg[(size_t)gx[r * MAX_NB + j] * HIDDEN + kc];
                }
            }
            As[kk * ASTR + r] = v;
        }
        __syncthreads();
#pragma unroll
        for (int kk = 0; kk < BK; ++kk) {
            const float4 bq = *(const float4*)&Bs[kk * BSTR + c0];
            const float  b4 = Bs[kk * BSTR + c4];
            const float4 a0 = *(const float4*)&As[kk * ASTR + wave * 8];
            const float4 a1 = *(const float4*)&As[kk * ASTR + wave * 8 + 4];
            const float ar8[8] = {a0.x, a0.y, a0.z, a0.w, a1.x, a1.y, a1.z, a1.w};
#pragma unroll
            for (int r = 0; r < 8; ++r) {
                acc[r][0] = fmaf(ar8[r], bq.x, acc[r][0]);
                acc[r][1] = fmaf(ar8[r], bq.y, acc[r][1]);
                acc[r][2] = fmaf(ar8[r], bq.z, acc[r][2]);
                acc[r][3] = fmaf(ar8[r], bq.w, acc[r][3]);
                acc[r][4] = fmaf(ar8[r], b4,   acc[r][4]);
            }
        }
        __syncthreads();
    }

    if (MODE == 4) {
        const float4 bqv = *(const float4*)&bias[c0];
        const float  b4v = bias[c4];
        float s0 = 0, s1 = 0, s2 = 0, s3 = 0, s4 = 0;
#pragma unroll
        for (int r = 0; r < 8; ++r) {
            s0 += fmaxf(acc[r][0] + bqv.x, 0.f);
            s1 += fmaxf(acc[r][1] + bqv.y, 0.f);
            s2 += fmaxf(acc[r][2] + bqv.z, 0.f);
            s3 += fmaxf(acc[r][3] + bqv.w, 0.f);
            s4 += fmaxf(acc[r][4] + b4v,   0.f);
        }
        float* wsum = Bs;
        *(float4*)&wsum[wave * BSTR + c0] = make_float4(s0, s1, s2, s3);
        if (has4) wsum[wave * BSTR + c4] = s4;
        __syncthreads();
        const int m0 = blockIdx.x * 2;
        for (int t = tid; t < 2 * HIDDEN; t += 512) {
            const int m = t / HIDDEN, col = t - m * HIDDEN;
            const float v = wsum[(4 * m + 0) * BSTR + col] + wsum[(4 * m + 1) * BSTR + col]
                          + wsum[(4 * m + 2) * BSTR + col] + wsum[(4 * m + 3) * BSTR + col]
                          + hsum[(size_t)(m0 + m) * HIDDEN + col];
            out0[(size_t)(m0 + m) * HIDDEN + col] = v * (1.f / 32.f);
        }
        return;
    }

#pragma unroll
    for (int r = 0; r < 8; ++r) {
        const size_t off = (size_t)(row0 + wave * 8 + r) * HIDDEN;
        float4 v = make_float4(acc[r][0], acc[r][1], acc[r][2], acc[r][3]);
        float v4 = acc[r][4];
        if (MODE == 0) {
            *(float4*)&out0[off + c0] = v;
            if (has4) out0[off + c4] = v4;
            float4 rv = make_float4(fmaxf(v.x,0.f), fmaxf(v.y,0.f), fmaxf(v.z,0.f), fmaxf(v.w,0.f));
            *(float4*)&out1[off + c0] = rv;
            if (has4) out1[off + c4] = fmaxf(v4, 0.f);
        } else if (MODE == 1) {
            const float4 bi = *(const float4*)&binput[off + c0];
            float4 rv = make_float4(fmaxf(bi.x+v.x,0.f), fmaxf(bi.y+v.y,0.f),
                                    fmaxf(bi.z+v.z,0.f), fmaxf(bi.w+v.w,0.f));
            *(float4*)&out0[off + c0] = rv;
            if (has4) out0[off + c4] = fmaxf(binput[off + c4] + v4, 0.f);
        } else if (MODE == 2) {
            const float4 bb = *(const float4*)&bias[c0];
            float4 rv = make_float4(fmaxf(v.x+bb.x,0.f), fmaxf(v.y+bb.y,0.f),
                                    fmaxf(v.z+bb.z,0.f), fmaxf(v.w+bb.w,0.f));
            *(float4*)&out0[off + c0] = rv;
            if (has4) out0[off + c4] = fmaxf(v4 + bias[c4], 0.f);
        } else {
            *(float4*)&out0[off + c0] = v;
            if (has4) out0[off + c4] = v4;
        }
    }
}

// ---------------------------------------------------------------------------
// Per-molecule middle stage (R6-proven): logits, softmax, P = att@h, hsum.
// ---------------------------------------------------------------------------
#define HSTR 320

__device__ __forceinline__ int hsw(int a, int c4u) {
    return a * HSTR + ((c4u ^ (a & 7)) << 2);
}

__global__ __launch_bounds__(512)
void attn_mid(const float* __restrict__ atom_h,
              const float* __restrict__ q_all,
              float* __restrict__ P_all,
              float* __restrict__ hsum)
{
    __shared__ float hs[APM * HSTR];
    __shared__ float qs[APM * HIDDEN];
    __shared__ float att[APM][33];

    const int tid  = threadIdx.x;
    const int wave = tid >> 6;
    const int lane = tid & 63;
    const int mol  = blockIdx.x;
    const float* hb = atom_h + (size_t)mol * APM * HIDDEN;
    const float* qb = q_all  + (size_t)mol * APM * HIDDEN;

    for (int j = tid; j < APM * 75; j += 512) {
        const int a = j / 75, c4u = j - a * 75;
        *(float4*)&hs[hsw(a, c4u)] = *(const float4*)&hb[(size_t)a * HIDDEN + 4 * c4u];
    }
    for (int j = tid; j < APM * 75; j += 512)
        *(float4*)&qs[4 * j] = *(const float4*)&qb[4 * j];
    __syncthreads();

    {
        const int a = tid >> 5, b = tid & 31;
        float s0 = 0.f, s1 = 0.f;
        for (int t = 0; t < 75; ++t) {
            const float4 hv = *(const float4*)&hs[hsw(b, t)];
            const float4 q0 = *(const float4*)&qs[a * HIDDEN + 4 * t];
            const float4 q1 = *(const float4*)&qs[(a + 16) * HIDDEN + 4 * t];
            s0 = fmaf(q0.x, hv.x, fmaf(q0.y, hv.y, fmaf(q0.z, hv.z, fmaf(q0.w, hv.w, s0))));
            s1 = fmaf(q1.x, hv.x, fmaf(q1.y, hv.y, fmaf(q1.z, hv.z, fmaf(q1.w, hv.w, s1))));
        }
        att[a][b] = s0;
        att[a + 16][b] = s1;
    }
    __syncthreads();

    if (tid < APM) {
        float m = -3.4e38f;
#pragma unroll 4
        for (int b = 0; b < APM; ++b) m = fmaxf(m, att[tid][b]);
        float s = 0.f;
#pragma unroll 4
        for (int b = 0; b < APM; ++b) { const float e = __expf(att[tid][b] - m); att[tid][b] = e; s += e; }
        const float inv = 1.f / s;
#pragma unroll 4
        for (int b = 0; b < APM; ++b) att[tid][b] *= inv;
    }
    __syncthreads();

    {
        const int r0 = wave * 4;
        const int c0 = 4 * lane;
        const bool has4 = (lane < 44);
        const int c4u = 64 + (lane >> 2), c4r = lane & 3;
        float4 p[4];
        float  p4[4];
#pragma unroll
        for (int r = 0; r < 4; ++r) { p[r] = make_float4(0,0,0,0); p4[r] = 0.f; }
#pragma unroll 4
        for (int b = 0; b < APM; ++b) {
            const float4 hv = *(const float4*)&hs[hsw(b, lane)];
            const float  h4 = hs[hsw(b, c4u) + c4r];
#pragma unroll
            for (int r = 0; r < 4; ++r) {
                const float av = att[r0 + r][b];
                p[r].x = fmaf(av, hv.x, p[r].x);
                p[r].y = fmaf(av, hv.y, p[r].y);
                p[r].z = fmaf(av, hv.z, p[r].z);
                p[r].w = fmaf(av, hv.w, p[r].w);
                p4[r]  = fmaf(av, h4,   p4[r]);
            }
        }
#pragma unroll
        for (int r = 0; r < 4; ++r) {
            const size_t off = ((size_t)mol * APM + r0 + r) * HIDDEN;
            *(float4*)&P_all[off + c0] = p[r];
            if (has4) P_all[off + 256 + lane] = p4[r];
        }
    }

    if (tid < HIDDEN) {
        const int c4u = tid >> 2, cr = tid & 3;
        float s = 0.f;
#pragma unroll 4
        for (int a = 0; a < APM; ++a) s += hs[hsw(a, c4u) + cr];
        hsum[(size_t)mol * HIDDEN + tid] = s;
    }
}

// ---------------------------------------------------------------------------
extern "C" void kernel_launch(void* const* d_in, const int* in_sizes, int n_in,
                              void* d_out, int out_size, void* d_ws, size_t ws_size,
                              hipStream_t stream)
{
    const float* fatoms = (const float*)d_in[0];
    const float* fbonds = (const float*)d_in[1];
    const int*   agraph = (const int*)d_in[2];
    const int*   bgraph = (const int*)d_in[3];
    const float* W_i    = (const float*)d_in[4];
    const float* W_h    = (const float*)d_in[5];
    const float* W_o    = (const float*)d_in[6];
    const float* b_o    = (const float*)d_in[7];
    const float* W_a    = (const float*)d_in[8];
    const float* W_b    = (const float*)d_in[9];
    const float* b_b    = (const float*)d_in[10];
    float* out = (float*)d_out;

    const size_t BIG = (size_t)N_BONDS * HIDDEN;
    const size_t need = (3 * BIG + (size_t)N_MOLS * HIDDEN + WT_C * WT_K) * sizeof(float);
    float* base;
    if (ws_size >= need) {
        base = (float*)d_ws;
    } else {
        void* p = nullptr;
        (void)hipGetSymbolAddress(&p, HIP_SYMBOL(g_scratch));
        base = (float*)p;
    }
    float* binput = base;           // later: atom_h
    float* msg0   = base + BIG;     // later: q_all
    float* msg1   = base + 2 * BIG; // later: P_all
    float* hsum   = base + 3 * BIG;
    u16*   wt_hi  = (u16*)(base + 3 * BIG + (size_t)N_MOLS * HIDDEN);
    u16*   wt_lo  = wt_hi + WT_C * WT_K;
    float* atom_h = binput;
    float* q_all  = msg0;
    float* P_all  = msg1;

    const dim3 blk(512);

    // split/transpose W_h once per call
    wt_prep<<<(WT_C * WT_K + 255) / 256, dim3(256), 0, stream>>>(W_h, wt_hi, wt_lo);

    // binput = fbonds @ W_i ; msg0 = relu(binput)
    gemm_fused<0><<<N_BONDS / BM, blk, 0, stream>>>(
        fbonds, BOND_IN, nullptr, nullptr, W_i, nullptr, nullptr, nullptr,
        binput, msg0, BOND_IN);

    // 5 message-passing iterations — MFMA path
    const float* cur = msg0;
    float* nxt = msg1;
    for (int it = 0; it < 5; ++it) {
        mp_mfma<<<N_BONDS / 64, blk, 0, stream>>>(
            cur, bgraph, wt_hi, wt_lo, binput, nxt);
        float* t = nxt; nxt = (float*)cur; cur = t;
    }
    // final message in cur (= msg1)

    // atom_h = relu(concat(fatoms, gather(msg)) @ W_o + b_o)
    gemm_fused<2><<<N_ATOMS / BM, blk, 0, stream>>>(
        fatoms, ATOM_FDIM, cur, agraph, W_o, nullptr, b_o, nullptr,
        atom_h, nullptr, ATOM_FDIM + HIDDEN);

    // q_all = atom_h @ W_a
    gemm_fused<3><<<N_ATOMS / BM, blk, 0, stream>>>(
        atom_h, HIDDEN, nullptr, nullptr, W_a, nullptr, nullptr, nullptr,
        q_all, nullptr, HIDDEN);

    // per-molecule: logits, softmax, P = att@h, hsum
    attn_mid<<<N_MOLS, dim3(512), 0, stream>>>(atom_h, q_all, P_all, hsum);

    // out[mol] = (hsum + sum_rows relu(P @ W_b + b_b)) / 32
    gemm_fused<4><<<N_ATOMS / BM, blk, 0, stream>>>(
        P_all, HIDDEN, nullptr, nullptr, W_b, nullptr, b_b, hsum,
        out, nullptr, HIDDEN);
}

// Round 8
// 6973.476 us; speedup vs baseline: 1.7489x; 1.1352x over previous
//
#include <hip/hip_runtime.h>
#include <hip/hip_fp16.h>
#include <math.h>

#define HIDDEN 300
#define ATOM_FDIM 136
#define BOND_IN 148
#define MAX_NB 6
#define N_MOLS 4096
#define APM 32
#define N_ATOMS (N_MOLS*APM)
#define N_BONDS (2*N_ATOMS)

#define BK 16
#define BM 64
#define ASTR 68     // fp32-GEMM A-tile row stride (words)
#define BSTR 304    // fp32-GEMM B-tile row stride (words)

// Wt (split-bf16, transposed) geometry: [304 cols][320 k] per split
#define WT_C 304
#define WT_K 320

typedef unsigned short u16;
typedef short bf16x8 __attribute__((ext_vector_type(8)));
typedef float f32x4  __attribute__((ext_vector_type(4)));

// Fallback scratch if ws_size too small (same float count as the layout below).
__device__ float g_scratch[3ull * N_BONDS * HIDDEN + (size_t)N_MOLS * HIDDEN + WT_C * WT_K];

__device__ __forceinline__ u16 bf16_rne(float x) {
    unsigned u = __float_as_uint(x);
    unsigned r = (u + 0x7fffu + ((u >> 16) & 1u)) >> 16;
    return (u16)r;
}
__device__ __forceinline__ float bf16_f(u16 h) {
    return __uint_as_float(((unsigned)h) << 16);
}
__device__ __forceinline__ void st_h4(__half* p, float a, float b, float c, float d) {
    *(__half2*)(p)     = __floats2half2_rn(a, b);
    *(__half2*)(p + 2) = __floats2half2_rn(c, d);
}

// ---------------------------------------------------------------------------
// Prep: Wt_hi/Wt_lo[col][k] = split-bf16 of W_h[k][col], zero-padded to 304x320
// ---------------------------------------------------------------------------
__global__ __launch_bounds__(256)
void wt_prep(const float* __restrict__ W, u16* __restrict__ wt_hi, u16* __restrict__ wt_lo)
{
    const int i = blockIdx.x * 256 + threadIdx.x;
    if (i >= WT_C * WT_K) return;
    const int c = i / WT_K, k = i - c * WT_K;
    float w = (c < HIDDEN && k < HIDDEN) ? W[(size_t)k * HIDDEN + c] : 0.f;
    const u16 hi = bf16_rne(w);
    const u16 lo = bf16_rne(w - bf16_f(hi));
    wt_hi[i] = hi;
    wt_lo[i] = lo;
}

// ---------------------------------------------------------------------------
// Message-passing step via MFMA (split-bf16 math, fp16 STORAGE for msg/binput):
//   out0 = fp16( relu(binput + gather6(msg) @ W_h) )
// Structure identical to R7-passed kernel; only load/store dtypes changed.
// ---------------------------------------------------------------------------
__global__ __launch_bounds__(512)
void mp_mfma(const __half* __restrict__ msg,
             const int*   __restrict__ graph,
             const u16*   __restrict__ wt_hi,
             const u16*   __restrict__ wt_lo,
             const __half* __restrict__ binput,
             __half* __restrict__ out0)
{
    __shared__ u16 Ahi[64 * 40];
    __shared__ u16 Alo[64 * 40];
    __shared__ int gx[64 * MAX_NB];

    const int tid  = threadIdx.x;
    const int row0 = blockIdx.x * 64;

    if (tid < 64 * MAX_NB) gx[tid] = graph[(size_t)row0 * MAX_NB + tid];
    __syncthreads();

    const int w  = tid >> 6;          // wave 0..7
    const int l  = tid & 63;
    const int g  = l >> 4;            // k-chunk 0..3
    const int mr = (w & 3) * 16 + (l & 15);      // A-frag row (block-local)
    const int tbase = (w >> 2) ? 10 : 0;         // n-tile group
    const int ntile = (w >> 2) ? 9 : 10;

    const int sr = tid >> 3;          // stage row 0..63
    const int sk = (tid & 7) * 4;     // stage k-offset 0..28
    const int* sg = &gx[sr * MAX_NB];

    f32x4 acc[10];
#pragma unroll
    for (int t = 0; t < 10; ++t) acc[t] = (f32x4){0.f, 0.f, 0.f, 0.f};

    for (int k0 = 0; k0 < HIDDEN; k0 += 32) {
        // ---- stage A: fp16 gather -> fp32 sum -> split bf16 hi/lo
        // (k>=300 reads run past the row into adjacent scratch: finite values,
        //  and Wt is zero there, so products vanish — safe unguarded)
        const int kk = k0 + sk;
        float s0 = 0.f, s1 = 0.f, s2 = 0.f, s3 = 0.f;
#pragma unroll
        for (int j = 0; j < MAX_NB; ++j) {
            const __half2* p = (const __half2*)(msg + (size_t)sg[j] * HIDDEN + kk);
            const float2 u = __half22float2(p[0]);
            const float2 v = __half22float2(p[1]);
            s0 += u.x; s1 += u.y; s2 += v.x; s3 += v.y;
        }
        const u16 h0 = bf16_rne(s0), h1 = bf16_rne(s1), h2 = bf16_rne(s2), h3 = bf16_rne(s3);
        const u16 e0 = bf16_rne(s0 - bf16_f(h0)), e1 = bf16_rne(s1 - bf16_f(h1));
        const u16 e2 = bf16_rne(s2 - bf16_f(h2)), e3 = bf16_rne(s3 - bf16_f(h3));
        uint2 ph, pl;
        ph.x = (unsigned)h0 | ((unsigned)h1 << 16);
        ph.y = (unsigned)h2 | ((unsigned)h3 << 16);
        pl.x = (unsigned)e0 | ((unsigned)e1 << 16);
        pl.y = (unsigned)e2 | ((unsigned)e3 << 16);
        *(uint2*)&Ahi[sr * 40 + sk] = ph;
        *(uint2*)&Alo[sr * 40 + sk] = pl;
        __syncthreads();

        const bf16x8 ahi = *(const bf16x8*)&Ahi[mr * 40 + 8 * g];
        const bf16x8 alo = *(const bf16x8*)&Alo[mr * 40 + 8 * g];
        const int kb = k0 + 8 * g;

#pragma unroll
        for (int t = 0; t < 10; ++t) {
            if (t < ntile) {
                const int cn = 16 * (tbase + t) + (l & 15);
                const bf16x8 bhi = *(const bf16x8*)&wt_hi[(size_t)cn * WT_K + kb];
                const bf16x8 blo = *(const bf16x8*)&wt_lo[(size_t)cn * WT_K + kb];
                acc[t] = __builtin_amdgcn_mfma_f32_16x16x32_bf16(ahi, bhi, acc[t], 0, 0, 0);
                acc[t] = __builtin_amdgcn_mfma_f32_16x16x32_bf16(ahi, blo, acc[t], 0, 0, 0);
                acc[t] = __builtin_amdgcn_mfma_f32_16x16x32_bf16(alo, bhi, acc[t], 0, 0, 0);
            }
        }
        __syncthreads();
    }

    // ---- epilogue: D[row=(l>>4)*4+j][col=l&15] per tile (m89-verified map)
#pragma unroll
    for (int t = 0; t < 10; ++t) {
        if (t < ntile) {
            const int col = 16 * (tbase + t) + (l & 15);
            if (col < HIDDEN) {
#pragma unroll
                for (int j = 0; j < 4; ++j) {
                    const size_t off = (size_t)(row0 + (w & 3) * 16 + 4 * g + j) * HIDDEN + col;
                    out0[off] = __float2half(fmaxf(__half2float(binput[off]) + acc[t][j], 0.f));
                }
            }
        }
    }
}

// ---------------------------------------------------------------------------
// fp32 fused GEMM family (R6/R7-proven skeleton). 512 threads, BM=64, BK=16.
//  MODE 0: A=fbonds[lda]            -> out0=fp16(A@W), out1=fp16(relu(A@W))
//  MODE 2: A=concat(fatoms, gather from fp16 msg) -> out0=relu(A@W + bias)
//  MODE 3: A dense [lda]            -> out0=A@W
//  MODE 4: A dense (P_all)          -> out0[mol]=(hsum+sum_rows relu(A@W+bias))/32
// ---------------------------------------------------------------------------
template<int MODE>
__global__ __launch_bounds__(512)
void gemm_fused(const float* __restrict__ Adense, int lda,
                const void*  __restrict__ msgv,
                const int*   __restrict__ graph,
                const float* __restrict__ W,
                const float* __restrict__ bias,
                const float* __restrict__ hsum,
                float* __restrict__ out0,
                float* __restrict__ out1,
                int K)
{
    __shared__ float As[BK * ASTR];
    __shared__ float Bs[BK * BSTR];
    __shared__ int   gx[BM * MAX_NB];

    const int tid  = threadIdx.x;
    const int wave = tid >> 6;
    const int lane = tid & 63;
    const int row0 = blockIdx.x * BM;
    const int c0   = 4 * lane;
    const bool has4 = (lane < HIDDEN - 256);
    const int  c4   = has4 ? (256 + lane) : 256;

    if (MODE == 2) {
        if (tid < BM * MAX_NB) gx[tid] = graph[(size_t)row0 * MAX_NB + tid];
        __syncthreads();
    }

    float acc[8][5];
#pragma unroll
    for (int r = 0; r < 8; ++r)
#pragma unroll
        for (int c = 0; c < 5; ++c) acc[r][c] = 0.f;

    const int nk = (K + BK - 1) / BK;
    for (int kt = 0; kt < nk; ++kt) {
        const int k0 = kt * BK;
        for (int i = tid; i < BK * 300; i += 512) {
            const int kk = i / 300;
            const int col = i - kk * 300;
            const int k = k0 + kk;
            Bs[kk * BSTR + col] = (k < K) ? W[(size_t)k * HIDDEN + col] : 0.f;
        }
        for (int i = tid; i < BK * BM; i += 512) {
            const int r  = i >> 4;
            const int kk = i & 15;
            const int k  = k0 + kk;
            float v = 0.f;
            if (MODE == 0 || MODE == 3 || MODE == 4) {
                if (k < K) v = Adense[(size_t)(row0 + r) * lda + k];
            } else { // MODE 2: concat(fatoms[0:136], gather6 fp16 msg [136:436])
                if (k < ATOM_FDIM) {
                    v = Adense[(size_t)(row0 + r) * lda + k];
                } else if (k < K) {
                    const int kc = k - ATOM_FDIM;
                    const __half* mh = (const __half*)msgv;
#pragma unroll
                    for (int j = 0; j < MAX_NB; ++j)
                        v += __half2float(mh[(size_t)gx[r * MAX_NB + j] * HIDDEN + kc]);
                }
            }
            As[kk * ASTR + r] = v;
        }
        __syncthreads();
#pragma unroll
        for (int kk = 0; kk < BK; ++kk) {
            const float4 bq = *(const float4*)&Bs[kk * BSTR + c0];
            const float  b4 = Bs[kk * BSTR + c4];
            const float4 a0 = *(const float4*)&As[kk * ASTR + wave * 8];
            const float4 a1 = *(const float4*)&As[kk * ASTR + wave * 8 + 4];
            const float ar8[8] = {a0.x, a0.y, a0.z, a0.w, a1.x, a1.y, a1.z, a1.w};
#pragma unroll
            for (int r = 0; r < 8; ++r) {
                acc[r][0] = fmaf(ar8[r], bq.x, acc[r][0]);
                acc[r][1] = fmaf(ar8[r], bq.y, acc[r][1]);
                acc[r][2] = fmaf(ar8[r], bq.z, acc[r][2]);
                acc[r][3] = fmaf(ar8[r], bq.w, acc[r][3]);
                acc[r][4] = fmaf(ar8[r], b4,   acc[r][4]);
            }
        }
        __syncthreads();
    }

    if (MODE == 4) {
        const float4 bqv = *(const float4*)&bias[c0];
        const float  b4v = bias[c4];
        float s0 = 0, s1 = 0, s2 = 0, s3 = 0, s4 = 0;
#pragma unroll
        for (int r = 0; r < 8; ++r) {
            s0 += fmaxf(acc[r][0] + bqv.x, 0.f);
            s1 += fmaxf(acc[r][1] + bqv.y, 0.f);
            s2 += fmaxf(acc[r][2] + bqv.z, 0.f);
            s3 += fmaxf(acc[r][3] + bqv.w, 0.f);
            s4 += fmaxf(acc[r][4] + b4v,   0.f);
        }
        float* wsum = Bs;
        *(float4*)&wsum[wave * BSTR + c0] = make_float4(s0, s1, s2, s3);
        if (has4) wsum[wave * BSTR + c4] = s4;
        __syncthreads();
        const int m0 = blockIdx.x * 2;
        for (int t = tid; t < 2 * HIDDEN; t += 512) {
            const int m = t / HIDDEN, col = t - m * HIDDEN;
            const float v = wsum[(4 * m + 0) * BSTR + col] + wsum[(4 * m + 1) * BSTR + col]
                          + wsum[(4 * m + 2) * BSTR + col] + wsum[(4 * m + 3) * BSTR + col]
                          + hsum[(size_t)(m0 + m) * HIDDEN + col];
            out0[(size_t)(m0 + m) * HIDDEN + col] = v * (1.f / 32.f);
        }
        return;
    }

#pragma unroll
    for (int r = 0; r < 8; ++r) {
        const size_t off = (size_t)(row0 + wave * 8 + r) * HIDDEN;
        float4 v = make_float4(acc[r][0], acc[r][1], acc[r][2], acc[r][3]);
        float v4 = acc[r][4];
        if (MODE == 0) {
            __half* o0 = (__half*)out0;
            __half* o1 = (__half*)out1;
            st_h4(&o0[off + c0], v.x, v.y, v.z, v.w);
            if (has4) o0[off + c4] = __float2half(v4);
            st_h4(&o1[off + c0], fmaxf(v.x,0.f), fmaxf(v.y,0.f), fmaxf(v.z,0.f), fmaxf(v.w,0.f));
            if (has4) o1[off + c4] = __float2half(fmaxf(v4, 0.f));
        } else if (MODE == 2) {
            const float4 bb = *(const float4*)&bias[c0];
            float4 rv = make_float4(fmaxf(v.x+bb.x,0.f), fmaxf(v.y+bb.y,0.f),
                                    fmaxf(v.z+bb.z,0.f), fmaxf(v.w+bb.w,0.f));
            *(float4*)&out0[off + c0] = rv;
            if (has4) out0[off + c4] = fmaxf(v4 + bias[c4], 0.f);
        } else { // MODE 3
            *(float4*)&out0[off + c0] = v;
            if (has4) out0[off + c4] = v4;
        }
    }
}

// ---------------------------------------------------------------------------
// Per-molecule middle stage (R6/R7-proven): logits, softmax, P = att@h, hsum.
// ---------------------------------------------------------------------------
#define HSTR 320

__device__ __forceinline__ int hsw(int a, int c4u) {
    return a * HSTR + ((c4u ^ (a & 7)) << 2);
}

__global__ __launch_bounds__(512)
void attn_mid(const float* __restrict__ atom_h,
              const float* __restrict__ q_all,
              float* __restrict__ P_all,
              float* __restrict__ hsum)
{
    __shared__ float hs[APM * HSTR];
    __shared__ float qs[APM * HIDDEN];
    __shared__ float att[APM][33];

    const int tid  = threadIdx.x;
    const int wave = tid >> 6;
    const int lane = tid & 63;
    const int mol  = blockIdx.x;
    const float* hb = atom_h + (size_t)mol * APM * HIDDEN;
    const float* qb = q_all  + (size_t)mol * APM * HIDDEN;

    for (int j = tid; j < APM * 75; j += 512) {
        const int a = j / 75, c4u = j - a * 75;
        *(float4*)&hs[hsw(a, c4u)] = *(const float4*)&hb[(size_t)a * HIDDEN + 4 * c4u];
    }
    for (int j = tid; j < APM * 75; j += 512)
        *(float4*)&qs[4 * j] = *(const float4*)&qb[4 * j];
    __syncthreads();

    {
        const int a = tid >> 5, b = tid & 31;
        float s0 = 0.f, s1 = 0.f;
        for (int t = 0; t < 75; ++t) {
            const float4 hv = *(const float4*)&hs[hsw(b, t)];
            const float4 q0 = *(const float4*)&qs[a * HIDDEN + 4 * t];
            const float4 q1 = *(const float4*)&qs[(a + 16) * HIDDEN + 4 * t];
            s0 = fmaf(q0.x, hv.x, fmaf(q0.y, hv.y, fmaf(q0.z, hv.z, fmaf(q0.w, hv.w, s0))));
            s1 = fmaf(q1.x, hv.x, fmaf(q1.y, hv.y, fmaf(q1.z, hv.z, fmaf(q1.w, hv.w, s1))));
        }
        att[a][b] = s0;
        att[a + 16][b] = s1;
    }
    __syncthreads();

    if (tid < APM) {
        float m = -3.4e38f;
#pragma unroll 4
        for (int b = 0; b < APM; ++b) m = fmaxf(m, att[tid][b]);
        float s = 0.f;
#pragma unroll 4
        for (int b = 0; b < APM; ++b) { const float e = __expf(att[tid][b] - m); att[tid][b] = e; s += e; }
        const float inv = 1.f / s;
#pragma unroll 4
        for (int b = 0; b < APM; ++b) att[tid][b] *= inv;
    }
    __syncthreads();

    {
        const int r0 = wave * 4;
        const int c0 = 4 * lane;
        const bool has4 = (lane < 44);
        const int c4u = 64 + (lane >> 2), c4r = lane & 3;
        float4 p[4];
        float  p4[4];
#pragma unroll
        for (int r = 0; r < 4; ++r) { p[r] = make_float4(0,0,0,0); p4[r] = 0.f; }
#pragma unroll 4
        for (int b = 0; b < APM; ++b) {
            const float4 hv = *(const float4*)&hs[hsw(b, lane)];
            const float  h4 = hs[hsw(b, c4u) + c4r];
#pragma unroll
            for (int r = 0; r < 4; ++r) {
                const float av = att[r0 + r][b];
                p[r].x = fmaf(av, hv.x, p[r].x);
                p[r].y = fmaf(av, hv.y, p[r].y);
                p[r].z = fmaf(av, hv.z, p[r].z);
                p[r].w = fmaf(av, hv.w, p[r].w);
                p4[r]  = fmaf(av, h4,   p4[r]);
            }
        }
#pragma unroll
        for (int r = 0; r < 4; ++r) {
            const size_t off = ((size_t)mol * APM + r0 + r) * HIDDEN;
            *(float4*)&P_all[off + c0] = p[r];
            if (has4) P_all[off + 256 + lane] = p4[r];
        }
    }

    if (tid < HIDDEN) {
        const int c4u = tid >> 2, cr = tid & 3;
        float s = 0.f;
#pragma unroll 4
        for (int a = 0; a < APM; ++a) s += hs[hsw(a, c4u) + cr];
        hsum[(size_t)mol * HIDDEN + tid] = s;
    }
}

// ---------------------------------------------------------------------------
extern "C" void kernel_launch(void* const* d_in, const int* in_sizes, int n_in,
                              void* d_out, int out_size, void* d_ws, size_t ws_size,
                              hipStream_t stream)
{
    const float* fatoms = (const float*)d_in[0];
    const float* fbonds = (const float*)d_in[1];
    const int*   agraph = (const int*)d_in[2];
    const int*   bgraph = (const int*)d_in[3];
    const float* W_i    = (const float*)d_in[4];
    const float* W_h    = (const float*)d_in[5];
    const float* W_o    = (const float*)d_in[6];
    const float* b_o    = (const float*)d_in[7];
    const float* W_a    = (const float*)d_in[8];
    const float* W_b    = (const float*)d_in[9];
    const float* b_b    = (const float*)d_in[10];
    float* out = (float*)d_out;

    const size_t WB = (size_t)N_BONDS * HIDDEN;   // 78,643,200
    const size_t WA = (size_t)N_ATOMS * HIDDEN;   // 39,321,600
    // float-unit layout: binput_h(WB/2) | msgA(WB/2) | msgB(WB/2) |
    //                    atom_h(WA) | q_all(WA) | P_all(WA) | hsum | wt
    const size_t need = (3 * WB / 2 + 3 * WA + (size_t)N_MOLS * HIDDEN + WT_C * WT_K) * sizeof(float);
    float* base;
    if (ws_size >= need) {
        base = (float*)d_ws;
    } else {
        void* p = nullptr;
        (void)hipGetSymbolAddress(&p, HIP_SYMBOL(g_scratch));
        base = (float*)p;
    }
    __half* binput_h = (__half*)base;
    __half* msgA     = (__half*)(base + WB / 2);
    __half* msgB     = (__half*)(base + WB);
    float*  atom_h   = base + 3 * WB / 2;
    float*  q_all    = atom_h + WA;
    float*  P_all    = q_all + WA;
    float*  hsum     = P_all + WA;
    u16*    wt_hi    = (u16*)(hsum + (size_t)N_MOLS * HIDDEN);
    u16*    wt_lo    = wt_hi + WT_C * WT_K;

    const dim3 blk(512);

    // split/transpose W_h once per call
    wt_prep<<<(WT_C * WT_K + 255) / 256, dim3(256), 0, stream>>>(W_h, wt_hi, wt_lo);

    // binput_h = fp16(fbonds @ W_i) ; msgA = fp16(relu(...))
    gemm_fused<0><<<N_BONDS / BM, blk, 0, stream>>>(
        fbonds, BOND_IN, nullptr, nullptr, W_i, nullptr, nullptr,
        (float*)binput_h, (float*)msgA, BOND_IN);

    // 5 message-passing iterations — MFMA path, fp16 storage
    const __half* cur = msgA;
    __half* nxt = msgB;
    for (int it = 0; it < 5; ++it) {
        mp_mfma<<<N_BONDS / 64, blk, 0, stream>>>(
            cur, bgraph, wt_hi, wt_lo, binput_h, nxt);
        __half* t = nxt; nxt = (__half*)cur; cur = t;
    }
    // final message in cur

    // atom_h = relu(concat(fatoms, gather6(fp16 msg)) @ W_o + b_o)
    gemm_fused<2><<<N_ATOMS / BM, blk, 0, stream>>>(
        fatoms, ATOM_FDIM, (const void*)cur, agraph, W_o, b_o, nullptr,
        atom_h, nullptr, ATOM_FDIM + HIDDEN);

    // q_all = atom_h @ W_a
    gemm_fused<3><<<N_ATOMS / BM, blk, 0, stream>>>(
        atom_h, HIDDEN, nullptr, nullptr, W_a, nullptr, nullptr,
        q_all, nullptr, HIDDEN);

    // per-molecule: logits, softmax, P = att@h, hsum
    attn_mid<<<N_MOLS, dim3(512), 0, stream>>>(atom_h, q_all, P_all, hsum);

    // out[mol] = (hsum + sum_rows relu(P @ W_b + b_b)) / 32
    gemm_fused<4><<<N_ATOMS / BM, blk, 0, stream>>>(
        P_all, HIDDEN, nullptr, nullptr, W_b, b_b, hsum,
        out, nullptr, HIDDEN);
}